// Round 5
// baseline (311.888 us; speedup 1.0000x reference)
//
#include <hip/hip_runtime.h>
#include <cstdint>

namespace {

constexpr int W = 256;
constexpr int ITERS = 10;
constexpr int PSTRIDE = 260;  // partial-row stride (floats): must be >= 256
                              // (row holds 256 partials), 16B-aligned, odd
                              // multiple of 4 banks. R4's 252 overlapped rows
                              // (race) -> garbage. Keep 260.

// One block per (n,h) matrix. 1024 threads; thread (tr=tid>>5, tc=tid&31)
// owns the 8x8 tile rows [8tr,8tr+8) x cols [8tc,8tc+8) of E = exp(attn),
// kept in registers for all 10 Sinkhorn iterations (exp-domain recursion:
// no transcendentals after the initial exp).
//
// R2: all E[][] accesses compile-time indexed (dynamic index -> scratch demotion).
// R3: waves_per_eu(4,4) attempt — backend ignored it, kept 64-VGPR budget.
// R5: LDS > 80KiB forces 1 block/CU -> 4 waves/EU -> 128-VGPR budget so
//     E (64 regs) stays resident (R4 tested this but had the PSTRIDE bug).
__global__ __attribute__((amdgpu_flat_work_group_size(1024, 1024),
                          amdgpu_waves_per_eu(4, 4)))
void sinkhorn_disp_kernel(
    const float* __restrict__ attn,
    const float* __restrict__ phi_p,
    float* __restrict__ out,
    int nh)
{
  // union sized by part.a: 32*320*8 = 81,920 B  (> 163840/2: forces 1 block/CU)
  __shared__ union {
    float f[32][PSTRIDE];             // GEMV partials
    unsigned long long a[32][320];    // argmax partials + LDS-size forcing
  } part;
  __shared__ float eu[W + 1];
  __shared__ float ev[W + 1];
  __shared__ float win[W][4];
  __shared__ int   jmax[W];
  __shared__ float Seu_s, Sev_s, ephi_s;

  const int tid = threadIdx.x;
  const int tc  = tid & 31;
  const int tr  = tid >> 5;
  const int bid = blockIdx.x;

  // ---- load + exp (the only big HBM traffic: 256 KB/block) ----
  float E[8][8];
  {
    const float* src = attn + (size_t)bid * (W * W) + (size_t)(tr * 8) * W + tc * 8;
    #pragma unroll
    for (int a = 0; a < 8; ++a) {
      float4 x0 = *(const float4*)(src + a * W);
      float4 x1 = *(const float4*)(src + a * W + 4);
      E[a][0] = __expf(x0.x); E[a][1] = __expf(x0.y);
      E[a][2] = __expf(x0.z); E[a][3] = __expf(x0.w);
      E[a][4] = __expf(x1.x); E[a][5] = __expf(x1.y);
      E[a][6] = __expf(x1.z); E[a][7] = __expf(x1.w);
    }
  }
  if (tid <= W) eu[tid] = 1.0f;          // u0 = 0  -> eu = 1
  if (tid == 0) ephi_s = __expf(phi_p[0]);
  __syncthreads();

  const float inv2w = 1.0f / (2.0f * W); // mu_i = nu_i = 1/(2W) for i<W; 0.5 at dustbin

  for (int it = 0; it < ITERS; ++it) {
    // ---- column pass partials: cp[b] = sum_a E[a][b] * eu[8tr+a] ----
    {
      float4 u0 = *(const float4*)&eu[tr * 8];
      float4 u1 = *(const float4*)&eu[tr * 8 + 4];
      float ul[8] = {u0.x, u0.y, u0.z, u0.w, u1.x, u1.y, u1.z, u1.w};
      float cp[8];
      #pragma unroll
      for (int b = 0; b < 8; ++b) cp[b] = 0.0f;
      #pragma unroll
      for (int a = 0; a < 8; ++a) {
        #pragma unroll
        for (int b = 0; b < 8; ++b) cp[b] = __builtin_fmaf(E[a][b], ul[a], cp[b]);
      }
      float4* dst = (float4*)&part.f[tr][tc * 8];
      dst[0] = make_float4(cp[0], cp[1], cp[2], cp[3]);
      dst[1] = make_float4(cp[4], cp[5], cp[6], cp[7]);
    }
    // wave 0 (concurrently): Seu = sum_{i<=W} eu_i (for dustbin column)
    if (tid < 64) {
      float s = eu[tid] + eu[tid + 64] + eu[tid + 128] + eu[tid + 192];
      if (tid == 0) s += eu[W];
      #pragma unroll
      for (int off = 32; off > 0; off >>= 1) s += __shfl_xor(s, off, 64);
      if (tid == 0) Seu_s = s;
    }
    __syncthreads();
    // ---- column finalize: ev_j = nu_j / colsum_j ----
    if (tid < W) {
      float s = 0.0f;
      #pragma unroll
      for (int r = 0; r < 32; ++r) s += part.f[r][tid];   // stride-1, conflict-free
      s += ephi_s * eu[W];                                // dustbin row contribution
      ev[tid] = inv2w / s;
    } else if (tid == W) {
      ev[W] = 0.5f / (ephi_s * Seu_s);                    // dustbin column
    }
    __syncthreads();
    // ---- row pass partials: rp[a] = sum_b E[a][b] * ev[8tc+b] ----
    {
      float4 v0 = *(const float4*)&ev[tc * 8];
      float4 v1 = *(const float4*)&ev[tc * 8 + 4];
      float vl[8] = {v0.x, v0.y, v0.z, v0.w, v1.x, v1.y, v1.z, v1.w};
      float rp[8];
      #pragma unroll
      for (int a = 0; a < 8; ++a) rp[a] = 0.0f;
      #pragma unroll
      for (int b = 0; b < 8; ++b) {
        #pragma unroll
        for (int a = 0; a < 8; ++a) rp[a] = __builtin_fmaf(E[a][b], vl[b], rp[a]);
      }
      float4* dst = (float4*)&part.f[tc][tr * 8];
      dst[0] = make_float4(rp[0], rp[1], rp[2], rp[3]);
      dst[1] = make_float4(rp[4], rp[5], rp[6], rp[7]);
    }
    // wave 0: Sev = sum_{j<=W} ev_j (for dustbin row)
    if (tid < 64) {
      float s = ev[tid] + ev[tid + 64] + ev[tid + 128] + ev[tid + 192];
      if (tid == 0) s += ev[W];
      #pragma unroll
      for (int off = 32; off > 0; off >>= 1) s += __shfl_xor(s, off, 64);
      if (tid == 0) Sev_s = s;
    }
    __syncthreads();
    // ---- row finalize: eu_i = mu_i / rowsum_i ----
    if (tid < W) {
      float s = 0.0f;
      #pragma unroll
      for (int r = 0; r < 32; ++r) s += part.f[r][tid];
      s += ephi_s * ev[W];
      eu[tid] = inv2w / s;
    } else if (tid == W) {
      eu[W] = 0.5f / (ephi_s * Sev_s);
    }
    __syncthreads();
  }

  // ---- finale: P[i][j] = E*eu_i*ev_j*2W on the WxW block; argmax + 3-window ----
  if (tid < W) { win[tid][0] = 0.0f; win[tid][1] = 0.0f; win[tid][2] = 0.0f; }
  float vl[8];
  {
    float4 v0 = *(const float4*)&ev[tc * 8];
    float4 v1 = *(const float4*)&ev[tc * 8 + 4];
    vl[0] = v0.x; vl[1] = v0.y; vl[2] = v0.z; vl[3] = v0.w;
    vl[4] = v1.x; vl[5] = v1.y; vl[6] = v1.z; vl[7] = v1.w;
  }
  {
    #pragma unroll
    for (int a = 0; a < 8; ++a) {
      float m = -1.0f; int mj = 0;
      #pragma unroll
      for (int b = 0; b < 8; ++b) {
        float vv = E[a][b] * vl[b];           // eu_i*2W constant per row: drop
        if (vv > m) { m = vv; mj = tc * 8 + b; }   // strict > keeps first max
      }
      // pack (value, first-index-wins) for u64 max-reduce; values > 0 so
      // float bit pattern is order-preserving.
      part.a[tc][tr * 8 + a] =
          (((unsigned long long)__float_as_uint(m)) << 32) |
          (unsigned)(65535 - mj);
    }
  }
  __syncthreads();
  if (tid < W) {
    unsigned long long best = 0ull;
    #pragma unroll
    for (int r = 0; r < 32; ++r) {
      unsigned long long k = part.a[r][tid];
      best = (k > best) ? k : best;
    }
    jmax[tid] = 65535 - (int)(best & 0xffffffffull);
  }
  __syncthreads();
  // window scatter: the unique owner of column j writes P[i][j].
  // NOTE: b is a compile-time constant here; the dynamic index k hits LDS only.
  {
    float4 u0 = *(const float4*)&eu[tr * 8];
    float4 u1 = *(const float4*)&eu[tr * 8 + 4];
    float ul[8] = {u0.x, u0.y, u0.z, u0.w, u1.x, u1.y, u1.z, u1.w};
    #pragma unroll
    for (int a = 0; a < 8; ++a) {
      int i  = tr * 8 + a;
      int jm = jmax[i];
      #pragma unroll
      for (int b = 0; b < 8; ++b) {
        int k = (tc * 8 + b) - (jm - 1);
        if (k >= 0 && k < 3) {
          win[i][k] = E[a][b] * vl[b] * ul[a] * (2.0f * W);
        }
      }
    }
  }
  __syncthreads();
  if (tid < W) {
    const int i  = tid;
    const int jm = jmax[i];
    float w0 = win[i][0], w1 = win[i][1], w2 = win[i][2];
    float norm0 = w0 + w1 + w2;
    float norm  = (norm0 < 0.1f) ? 1.0f : norm0;
    // pos_shift padded with zero cols; out-of-range taps have w==0 anyway
    float p0 = fmaxf((float)(i - (jm - 1)), 0.0f);
    float p1 = fmaxf((float)(i - jm),       0.0f);
    float p2 = fmaxf((float)(i - (jm + 1)), 0.0f);
    float disp = (w0 / norm) * p0 + (w1 / norm) * p1 + (w2 / norm) * p2;
    float occ  = 1.0f - norm;
    out[(size_t)bid * W + i] = disp;
    out[(size_t)nh * W + (size_t)bid * W + i] = occ;
  }
}

} // namespace

extern "C" void kernel_launch(void* const* d_in, const int* in_sizes, int n_in,
                              void* d_out, int out_size, void* d_ws, size_t ws_size,
                              hipStream_t stream) {
  (void)n_in; (void)d_ws; (void)ws_size; (void)out_size;
  const float* attn = (const float*)d_in[0];
  const float* phi  = (const float*)d_in[1];
  float* out = (float*)d_out;
  const int nh = in_sizes[0] / (W * W);   // 4*120 = 480 matrices
  sinkhorn_disp_kernel<<<dim3(nh), dim3(1024), 0, stream>>>(attn, phi, out, nh);
}

// Round 6
// 307.707 us; speedup vs baseline: 1.0136x; 1.0136x over previous
//
#include <hip/hip_runtime.h>
#include <cstdint>

namespace {

constexpr int W = 256;
constexpr int ITERS = 10;
constexpr int PSTRIDE = 260;  // partial-row stride (floats): >=256, 16B-aligned,
                              // odd multiple of 4 banks (bank-conflict-free
                              // finalize reads). R4's 252 raced; keep 260.

// One block per (n,h) matrix. 1024 threads; thread (tr=tid>>5, tc=tid&31)
// owns the 8x8 tile rows [8tr,8tr+8) x cols [8tc,8tc+8) of E = exp(attn),
// kept in registers for all 10 Sinkhorn iterations (exp-domain recursion:
// no transcendentals after the initial exp).
//
// R2: all E[][] accesses compile-time indexed (dynamic index -> scratch demotion).
// R3: waves_per_eu(4,4) ignored (VGPR budget stayed 64, half of E spilled).
// R5: LDS-forced 1 block/CU also ignored by the budget heuristic (still 64).
// R6: amdgpu_num_vgpr(128) — sets the backend's VGPR budget DIRECTLY
//     (getMaxNumVGPRs returns the attribute, bypassing occupancy heuristics).
//     128 is the HW max for a 16-wave block (4 waves/EU x 128 = 512-reg file).
//     Also: argmax-partial row stride 321 u64 (R5's 320 was ≡0 mod 32 banks,
//     tripling SQ_LDS_BANK_CONFLICT).
__global__ __attribute__((amdgpu_flat_work_group_size(1024, 1024),
                          amdgpu_num_vgpr(128)))
void sinkhorn_disp_kernel(
    const float* __restrict__ attn,
    const float* __restrict__ phi_p,
    float* __restrict__ out,
    int nh)
{
  // union sized by part.a: 32*321*8 = 82,176 B (>81,920: forces 1 block/CU)
  __shared__ union {
    float f[32][PSTRIDE];             // GEMV partials
    unsigned long long a[32][321];    // argmax partials (stride ≡2 mod 32 banks)
  } part;
  __shared__ float eu[W + 1];
  __shared__ float ev[W + 1];
  __shared__ float win[W][4];
  __shared__ int   jmax[W];
  __shared__ float Seu_s, Sev_s, ephi_s;

  const int tid = threadIdx.x;
  const int tc  = tid & 31;
  const int tr  = tid >> 5;
  const int bid = blockIdx.x;

  // ---- load + exp (the only big HBM traffic: 256 KB/block) ----
  float E[8][8];
  {
    const float* src = attn + (size_t)bid * (W * W) + (size_t)(tr * 8) * W + tc * 8;
    #pragma unroll
    for (int a = 0; a < 8; ++a) {
      float4 x0 = *(const float4*)(src + a * W);
      float4 x1 = *(const float4*)(src + a * W + 4);
      E[a][0] = __expf(x0.x); E[a][1] = __expf(x0.y);
      E[a][2] = __expf(x0.z); E[a][3] = __expf(x0.w);
      E[a][4] = __expf(x1.x); E[a][5] = __expf(x1.y);
      E[a][6] = __expf(x1.z); E[a][7] = __expf(x1.w);
    }
  }
  if (tid <= W) eu[tid] = 1.0f;          // u0 = 0  -> eu = 1
  if (tid == 0) ephi_s = __expf(phi_p[0]);
  __syncthreads();

  const float inv2w = 1.0f / (2.0f * W); // mu_i = nu_i = 1/(2W) for i<W; 0.5 at dustbin

  for (int it = 0; it < ITERS; ++it) {
    // ---- column pass partials: cp[b] = sum_a E[a][b] * eu[8tr+a] ----
    {
      float4 u0 = *(const float4*)&eu[tr * 8];
      float4 u1 = *(const float4*)&eu[tr * 8 + 4];
      float ul[8] = {u0.x, u0.y, u0.z, u0.w, u1.x, u1.y, u1.z, u1.w};
      float cp[8];
      #pragma unroll
      for (int b = 0; b < 8; ++b) cp[b] = 0.0f;
      #pragma unroll
      for (int a = 0; a < 8; ++a) {
        #pragma unroll
        for (int b = 0; b < 8; ++b) cp[b] = __builtin_fmaf(E[a][b], ul[a], cp[b]);
      }
      float4* dst = (float4*)&part.f[tr][tc * 8];
      dst[0] = make_float4(cp[0], cp[1], cp[2], cp[3]);
      dst[1] = make_float4(cp[4], cp[5], cp[6], cp[7]);
    }
    // wave 0 (concurrently): Seu = sum_{i<=W} eu_i (for dustbin column)
    if (tid < 64) {
      float s = eu[tid] + eu[tid + 64] + eu[tid + 128] + eu[tid + 192];
      if (tid == 0) s += eu[W];
      #pragma unroll
      for (int off = 32; off > 0; off >>= 1) s += __shfl_xor(s, off, 64);
      if (tid == 0) Seu_s = s;
    }
    __syncthreads();
    // ---- column finalize: ev_j = nu_j / colsum_j ----
    if (tid < W) {
      float s = 0.0f;
      #pragma unroll
      for (int r = 0; r < 32; ++r) s += part.f[r][tid];   // stride-1, conflict-free
      s += ephi_s * eu[W];                                // dustbin row contribution
      ev[tid] = inv2w / s;
    } else if (tid == W) {
      ev[W] = 0.5f / (ephi_s * Seu_s);                    // dustbin column
    }
    __syncthreads();
    // ---- row pass partials: rp[a] = sum_b E[a][b] * ev[8tc+b] ----
    {
      float4 v0 = *(const float4*)&ev[tc * 8];
      float4 v1 = *(const float4*)&ev[tc * 8 + 4];
      float vl[8] = {v0.x, v0.y, v0.z, v0.w, v1.x, v1.y, v1.z, v1.w};
      float rp[8];
      #pragma unroll
      for (int a = 0; a < 8; ++a) rp[a] = 0.0f;
      #pragma unroll
      for (int b = 0; b < 8; ++b) {
        #pragma unroll
        for (int a = 0; a < 8; ++a) rp[a] = __builtin_fmaf(E[a][b], vl[b], rp[a]);
      }
      float4* dst = (float4*)&part.f[tc][tr * 8];
      dst[0] = make_float4(rp[0], rp[1], rp[2], rp[3]);
      dst[1] = make_float4(rp[4], rp[5], rp[6], rp[7]);
    }
    // wave 0: Sev = sum_{j<=W} ev_j (for dustbin row)
    if (tid < 64) {
      float s = ev[tid] + ev[tid + 64] + ev[tid + 128] + ev[tid + 192];
      if (tid == 0) s += ev[W];
      #pragma unroll
      for (int off = 32; off > 0; off >>= 1) s += __shfl_xor(s, off, 64);
      if (tid == 0) Sev_s = s;
    }
    __syncthreads();
    // ---- row finalize: eu_i = mu_i / rowsum_i ----
    if (tid < W) {
      float s = 0.0f;
      #pragma unroll
      for (int r = 0; r < 32; ++r) s += part.f[r][tid];
      s += ephi_s * ev[W];
      eu[tid] = inv2w / s;
    } else if (tid == W) {
      eu[W] = 0.5f / (ephi_s * Sev_s);
    }
    __syncthreads();
  }

  // ---- finale: P[i][j] = E*eu_i*ev_j*2W on the WxW block; argmax + 3-window ----
  if (tid < W) { win[tid][0] = 0.0f; win[tid][1] = 0.0f; win[tid][2] = 0.0f; }
  float vl[8];
  {
    float4 v0 = *(const float4*)&ev[tc * 8];
    float4 v1 = *(const float4*)&ev[tc * 8 + 4];
    vl[0] = v0.x; vl[1] = v0.y; vl[2] = v0.z; vl[3] = v0.w;
    vl[4] = v1.x; vl[5] = v1.y; vl[6] = v1.z; vl[7] = v1.w;
  }
  {
    #pragma unroll
    for (int a = 0; a < 8; ++a) {
      float m = -1.0f; int mj = 0;
      #pragma unroll
      for (int b = 0; b < 8; ++b) {
        float vv = E[a][b] * vl[b];           // eu_i*2W constant per row: drop
        if (vv > m) { m = vv; mj = tc * 8 + b; }   // strict > keeps first max
      }
      // pack (value, first-index-wins) for u64 max-reduce; values > 0 so
      // float bit pattern is order-preserving.
      part.a[tc][tr * 8 + a] =
          (((unsigned long long)__float_as_uint(m)) << 32) |
          (unsigned)(65535 - mj);
    }
  }
  __syncthreads();
  if (tid < W) {
    unsigned long long best = 0ull;
    #pragma unroll
    for (int r = 0; r < 32; ++r) {
      unsigned long long k = part.a[r][tid];
      best = (k > best) ? k : best;
    }
    jmax[tid] = 65535 - (int)(best & 0xffffffffull);
  }
  __syncthreads();
  // window scatter: the unique owner of column j writes P[i][j].
  // NOTE: b is a compile-time constant here; the dynamic index k hits LDS only.
  {
    float4 u0 = *(const float4*)&eu[tr * 8];
    float4 u1 = *(const float4*)&eu[tr * 8 + 4];
    float ul[8] = {u0.x, u0.y, u0.z, u0.w, u1.x, u1.y, u1.z, u1.w};
    #pragma unroll
    for (int a = 0; a < 8; ++a) {
      int i  = tr * 8 + a;
      int jm = jmax[i];
      #pragma unroll
      for (int b = 0; b < 8; ++b) {
        int k = (tc * 8 + b) - (jm - 1);
        if (k >= 0 && k < 3) {
          win[i][k] = E[a][b] * vl[b] * ul[a] * (2.0f * W);
        }
      }
    }
  }
  __syncthreads();
  if (tid < W) {
    const int i  = tid;
    const int jm = jmax[i];
    float w0 = win[i][0], w1 = win[i][1], w2 = win[i][2];
    float norm0 = w0 + w1 + w2;
    float norm  = (norm0 < 0.1f) ? 1.0f : norm0;
    // pos_shift padded with zero cols; out-of-range taps have w==0 anyway
    float p0 = fmaxf((float)(i - (jm - 1)), 0.0f);
    float p1 = fmaxf((float)(i - jm),       0.0f);
    float p2 = fmaxf((float)(i - (jm + 1)), 0.0f);
    float disp = (w0 / norm) * p0 + (w1 / norm) * p1 + (w2 / norm) * p2;
    float occ  = 1.0f - norm;
    out[(size_t)bid * W + i] = disp;
    out[(size_t)nh * W + (size_t)bid * W + i] = occ;
  }
}

} // namespace

extern "C" void kernel_launch(void* const* d_in, const int* in_sizes, int n_in,
                              void* d_out, int out_size, void* d_ws, size_t ws_size,
                              hipStream_t stream) {
  (void)n_in; (void)d_ws; (void)ws_size; (void)out_size;
  const float* attn = (const float*)d_in[0];
  const float* phi  = (const float*)d_in[1];
  float* out = (float*)d_out;
  const int nh = in_sizes[0] / (W * W);   // 4*120 = 480 matrices
  sinkhorn_disp_kernel<<<dim3(nh), dim3(1024), 0, stream>>>(attn, phi, out, nh);
}

// Round 7
// 246.569 us; speedup vs baseline: 1.2649x; 1.2480x over previous
//
#include <hip/hip_runtime.h>
#include <cstdint>

namespace {

constexpr int W = 256;
constexpr int ITERS = 10;
constexpr int PSTR = 260;   // partial row stride (floats): >=256, 16B multiple,
                            // odd multiple of 4 banks.
constexpr int NG = 16;      // partial groups (after in-wave shfl pre-combine)

// One block per (n,h) matrix, 1024 threads; thread (tr=tid>>5, tc=tid&31)
// owns the 8x8 tile rows [8tr,8tr+8) x cols [8tc,8tc+8) of E = exp(attn).
//
// R7: the toolchain pins 16-wave workgroups to a 64-VGPR budget (R3/R5/R6
// falsified every occupancy/attr knob), so fp32 E cannot be all-registers.
// Split: tile rows 0..3 in VGPRs (32 floats), rows 4..7 in LDS (128 KB),
// XOR-swizzled 16B chunks -> conflict-free ds_read_b128. Partials shrink to
// 16 groups via one __shfl_xor pre-combine; argmax LDS buffer replaced by a
// packed-u64 half-wave butterfly. Total LDS ~155 KB (1 block/CU).
__global__ __launch_bounds__(1024)
void sinkhorn_disp_kernel(
    const float* __restrict__ attn,
    const float* __restrict__ phi_p,
    float* __restrict__ out,
    int nh)
{
  __shared__ __align__(16) float E_lds[1024 * 32];   // 128 KB, rows 4..7
  __shared__ __align__(16) float fpart[NG][PSTR];    // 16.6 KB GEMV partials
  __shared__ __align__(16) float eu[W + 4];
  __shared__ __align__(16) float ev[W + 4];
  __shared__ __align__(16) float win[W][4];
  __shared__ int   jmax[W];
  __shared__ float Seu_s, Sev_s, ephi_s;

  const int tid = threadIdx.x;
  const int tc  = tid & 31;
  const int tr  = tid >> 5;
  const int bid = blockIdx.x;
  const int sw  = tid & 7;                  // chunk swizzle key
  float* myE = &E_lds[tid * 32];
  // chunk c (0..7) <-> tile row a=4+(c>>1), cols (c&1)*4 .. +3
  #define RDCH(c) (*(const float4*)&myE[4 * ((c) ^ sw)])

  // ---- load + exp: rows 0..3 -> registers, rows 4..7 -> swizzled LDS ----
  float Er[4][8];
  {
    const float* src = attn + (size_t)bid * (W * W) + (size_t)(tr * 8) * W + tc * 8;
    #pragma unroll
    for (int a = 0; a < 4; ++a) {
      float4 x0 = *(const float4*)(src + a * W);
      float4 x1 = *(const float4*)(src + a * W + 4);
      Er[a][0] = __expf(x0.x); Er[a][1] = __expf(x0.y);
      Er[a][2] = __expf(x0.z); Er[a][3] = __expf(x0.w);
      Er[a][4] = __expf(x1.x); Er[a][5] = __expf(x1.y);
      Er[a][6] = __expf(x1.z); Er[a][7] = __expf(x1.w);
    }
    #pragma unroll
    for (int ap = 0; ap < 4; ++ap) {
      float4 x0 = *(const float4*)(src + (4 + ap) * W);
      float4 x1 = *(const float4*)(src + (4 + ap) * W + 4);
      float4 e0 = make_float4(__expf(x0.x), __expf(x0.y), __expf(x0.z), __expf(x0.w));
      float4 e1 = make_float4(__expf(x1.x), __expf(x1.y), __expf(x1.z), __expf(x1.w));
      *(float4*)&myE[4 * ((2 * ap)     ^ sw)] = e0;
      *(float4*)&myE[4 * ((2 * ap + 1) ^ sw)] = e1;
    }
  }
  if (tid <= W) eu[tid] = 1.0f;            // u0 = 0 -> eu = 1
  if (tid == 0) ephi_s = __expf(phi_p[0]);
  __syncthreads();

  const float inv2w = 1.0f / (2.0f * W);

  for (int it = 0; it < ITERS; ++it) {
    // ---- column pass: cp[b] = sum_a E[a][b] * eu[8tr+a] ----
    {
      float4 u0 = *(const float4*)&eu[tr * 8];
      float4 u1 = *(const float4*)&eu[tr * 8 + 4];
      float ul[8] = {u0.x, u0.y, u0.z, u0.w, u1.x, u1.y, u1.z, u1.w};
      float cp[8];
      #pragma unroll
      for (int b = 0; b < 8; ++b) cp[b] = 0.0f;
      #pragma unroll
      for (int a = 0; a < 4; ++a) {
        #pragma unroll
        for (int b = 0; b < 8; ++b) cp[b] = __builtin_fmaf(Er[a][b], ul[a], cp[b]);
      }
      #pragma unroll
      for (int ap = 0; ap < 4; ++ap) {
        float4 e0 = RDCH(2 * ap), e1 = RDCH(2 * ap + 1);
        float ua = ul[4 + ap];
        cp[0] = __builtin_fmaf(e0.x, ua, cp[0]);
        cp[1] = __builtin_fmaf(e0.y, ua, cp[1]);
        cp[2] = __builtin_fmaf(e0.z, ua, cp[2]);
        cp[3] = __builtin_fmaf(e0.w, ua, cp[3]);
        cp[4] = __builtin_fmaf(e1.x, ua, cp[4]);
        cp[5] = __builtin_fmaf(e1.y, ua, cp[5]);
        cp[6] = __builtin_fmaf(e1.z, ua, cp[6]);
        cp[7] = __builtin_fmaf(e1.w, ua, cp[7]);
      }
      // combine tr-parity pair (lanes tc <-> tc+32 of this wave)
      #pragma unroll
      for (int b = 0; b < 8; ++b) cp[b] += __shfl_xor(cp[b], 32, 64);
      if (!(tr & 1)) {
        float4* dst = (float4*)&fpart[tr >> 1][tc * 8];
        dst[0] = make_float4(cp[0], cp[1], cp[2], cp[3]);
        dst[1] = make_float4(cp[4], cp[5], cp[6], cp[7]);
      }
    }
    if (tid < 64) {   // wave 0: Seu = sum_{i<=W} eu_i
      float s = eu[tid] + eu[tid + 64] + eu[tid + 128] + eu[tid + 192];
      if (tid == 0) s += eu[W];
      #pragma unroll
      for (int off = 32; off > 0; off >>= 1) s += __shfl_xor(s, off, 64);
      if (tid == 0) Seu_s = s;
    }
    __syncthreads();
    // ---- column finalize ----
    if (tid < W) {
      float s = 0.0f;
      #pragma unroll
      for (int g = 0; g < NG; ++g) s += fpart[g][tid];
      s += ephi_s * eu[W];
      ev[tid] = inv2w / s;
    } else if (tid == W) {
      ev[W] = 0.5f / (ephi_s * Seu_s);
    }
    __syncthreads();
    // ---- row pass: rp[a] = sum_b E[a][b] * ev[8tc+b] ----
    {
      float4 v0 = *(const float4*)&ev[tc * 8];
      float4 v1 = *(const float4*)&ev[tc * 8 + 4];
      float vl[8] = {v0.x, v0.y, v0.z, v0.w, v1.x, v1.y, v1.z, v1.w};
      float rp[8];
      #pragma unroll
      for (int a = 0; a < 8; ++a) rp[a] = 0.0f;
      #pragma unroll
      for (int a = 0; a < 4; ++a) {
        #pragma unroll
        for (int b = 0; b < 8; ++b) rp[a] = __builtin_fmaf(Er[a][b], vl[b], rp[a]);
      }
      #pragma unroll
      for (int ap = 0; ap < 4; ++ap) {
        float4 e0 = RDCH(2 * ap), e1 = RDCH(2 * ap + 1);
        float s = e0.x * vl[0] + e0.y * vl[1] + e0.z * vl[2] + e0.w * vl[3]
                + e1.x * vl[4] + e1.y * vl[5] + e1.z * vl[6] + e1.w * vl[7];
        rp[4 + ap] = s;
      }
      // combine tc-halves (lanes tc <-> tc^16, same half-wave, same rows)
      #pragma unroll
      for (int a = 0; a < 8; ++a) rp[a] += __shfl_xor(rp[a], 16, 64);
      if (!(tc & 16)) {
        float4* dst = (float4*)&fpart[tc][tr * 8];
        dst[0] = make_float4(rp[0], rp[1], rp[2], rp[3]);
        dst[1] = make_float4(rp[4], rp[5], rp[6], rp[7]);
      }
    }
    if (tid < 64) {   // wave 0: Sev = sum_{j<=W} ev_j
      float s = ev[tid] + ev[tid + 64] + ev[tid + 128] + ev[tid + 192];
      if (tid == 0) s += ev[W];
      #pragma unroll
      for (int off = 32; off > 0; off >>= 1) s += __shfl_xor(s, off, 64);
      if (tid == 0) Sev_s = s;
    }
    __syncthreads();
    // ---- row finalize ----
    if (tid < W) {
      float s = 0.0f;
      #pragma unroll
      for (int g = 0; g < NG; ++g) s += fpart[g][tid];
      s += ephi_s * ev[W];
      eu[tid] = inv2w / s;
    } else if (tid == W) {
      eu[W] = 0.5f / (ephi_s * Sev_s);
    }
    __syncthreads();
  }

  // ---- finale: argmax over P[i][j] ~ E[i][j]*ev[j] + 3-tap window ----
  if (tid < W) { win[tid][0] = 0.0f; win[tid][1] = 0.0f; win[tid][2] = 0.0f; }
  float vl[8];
  {
    float4 v0 = *(const float4*)&ev[tc * 8];
    float4 v1 = *(const float4*)&ev[tc * 8 + 4];
    vl[0] = v0.x; vl[1] = v0.y; vl[2] = v0.z; vl[3] = v0.w;
    vl[4] = v1.x; vl[5] = v1.y; vl[6] = v1.z; vl[7] = v1.w;
  }
  {
    #pragma unroll
    for (int a = 0; a < 8; ++a) {
      float m = -1.0f; int mj = 0;
      if (a < 4) {
        #pragma unroll
        for (int b = 0; b < 8; ++b) {
          float vv = Er[a < 4 ? a : 0][b] * vl[b];
          if (vv > m) { m = vv; mj = tc * 8 + b; }   // strict > : first max
        }
      } else {
        float4 e0 = RDCH(2 * (a - 4)), e1 = RDCH(2 * (a - 4) + 1);
        float e8[8] = {e0.x, e0.y, e0.z, e0.w, e1.x, e1.y, e1.z, e1.w};
        #pragma unroll
        for (int b = 0; b < 8; ++b) {
          float vv = e8[b] * vl[b];
          if (vv > m) { m = vv; mj = tc * 8 + b; }
        }
      }
      // pack (value, first-index-wins); values > 0 so float bits order-preserve
      unsigned long long best =
          (((unsigned long long)__float_as_uint(m)) << 32) |
          (unsigned)(65535 - mj);
      #pragma unroll
      for (int off = 16; off > 0; off >>= 1) {
        unsigned long long o = __shfl_xor(best, off, 64);
        best = (o > best) ? o : best;
      }
      if (tc == 0) jmax[tr * 8 + a] = 65535 - (int)(best & 0xffffffffull);
    }
  }
  __syncthreads();
  // window scatter: unique owner of column j writes P[i][j]
  {
    float4 u0 = *(const float4*)&eu[tr * 8];
    float4 u1 = *(const float4*)&eu[tr * 8 + 4];
    float ul[8] = {u0.x, u0.y, u0.z, u0.w, u1.x, u1.y, u1.z, u1.w};
    #pragma unroll
    for (int a = 0; a < 8; ++a) {
      int i  = tr * 8 + a;
      int jm = jmax[i];
      float e8[8];
      if (a < 4) {
        #pragma unroll
        for (int b = 0; b < 8; ++b) e8[b] = Er[a < 4 ? a : 0][b];
      } else {
        float4 e0 = RDCH(2 * (a - 4)), e1 = RDCH(2 * (a - 4) + 1);
        e8[0] = e0.x; e8[1] = e0.y; e8[2] = e0.z; e8[3] = e0.w;
        e8[4] = e1.x; e8[5] = e1.y; e8[6] = e1.z; e8[7] = e1.w;
      }
      #pragma unroll
      for (int b = 0; b < 8; ++b) {
        int k = (tc * 8 + b) - (jm - 1);
        if (k >= 0 && k < 3) {
          win[i][k] = e8[b] * vl[b] * ul[a] * (2.0f * W);
        }
      }
    }
  }
  __syncthreads();
  if (tid < W) {
    const int i  = tid;
    const int jm = jmax[i];
    float w0 = win[i][0], w1 = win[i][1], w2 = win[i][2];
    float norm0 = w0 + w1 + w2;
    float norm  = (norm0 < 0.1f) ? 1.0f : norm0;
    float p0 = fmaxf((float)(i - (jm - 1)), 0.0f);
    float p1 = fmaxf((float)(i - jm),       0.0f);
    float p2 = fmaxf((float)(i - (jm + 1)), 0.0f);
    float disp = (w0 / norm) * p0 + (w1 / norm) * p1 + (w2 / norm) * p2;
    float occ  = 1.0f - norm;
    out[(size_t)bid * W + i] = disp;
    out[(size_t)nh * W + (size_t)bid * W + i] = occ;
  }
  #undef RDCH
}

} // namespace

extern "C" void kernel_launch(void* const* d_in, const int* in_sizes, int n_in,
                              void* d_out, int out_size, void* d_ws, size_t ws_size,
                              hipStream_t stream) {
  (void)n_in; (void)d_ws; (void)ws_size; (void)out_size;
  const float* attn = (const float*)d_in[0];
  const float* phi  = (const float*)d_in[1];
  float* out = (float*)d_out;
  const int nh = in_sizes[0] / (W * W);   // 4*120 = 480 matrices
  sinkhorn_disp_kernel<<<dim3(nh), dim3(1024), 0, stream>>>(attn, phi, out, nh);
}